// Round 9
// baseline (5697.760 us; speedup 1.0000x reference)
//
#include <hip/hip_runtime.h>
#include <math.h>

#define B 32
#define T 128
#define H 512
#define E 512
#define ODIM 256
#define STEPS 16
#define G3 1536
#define BH (B * H)

typedef float4 f4;
typedef unsigned int uint32;
typedef unsigned short ushort;

__device__ __forceinline__ float sigmoidf_(float x) { return 1.0f / (1.0f + __expf(-x)); }
__device__ __forceinline__ float tanh_fast(float x) {
    float t = __expf(-2.0f * fabsf(x));
    float r = (1.0f - t) / (1.0f + t);
    return __builtin_copysignf(r, x);
}
__device__ __forceinline__ float dot4(const f4 a, const f4 b) {
    return fmaf(a.x, b.x, fmaf(a.y, b.y, fmaf(a.z, b.z, a.w * b.w)));
}
__device__ __forceinline__ float bfu(ushort u) {
    union { uint32 x; float f; } a; a.x = ((uint32)u) << 16; return a.f;
}
__device__ __forceinline__ void bf2x(uint32 v, float& lo, float& hi) {
    union { uint32 u; float f; } a, b;
    a.u = v << 16; b.u = v & 0xffff0000u;
    lo = a.f; hi = b.f;
}
__device__ __forceinline__ float dot8bf(uint4 wv, const f4 hA, const f4 hB) {
    float w0, w1, w2, w3, w4, w5, w6, w7;
    bf2x(wv.x, w0, w1); bf2x(wv.y, w2, w3); bf2x(wv.z, w4, w5); bf2x(wv.w, w6, w7);
    float s = fmaf(w0, hA.x, w1 * hA.y);
    s = fmaf(w2, hA.z, s); s = fmaf(w3, hA.w, s);
    s = fmaf(w4, hB.x, s); s = fmaf(w5, hB.y, s);
    s = fmaf(w6, hB.z, s); s = fmaf(w7, hB.w, s);
    return s;
}
__device__ __forceinline__ ushort f2bf(float f) {
    union { float f; uint32 u; } a; a.f = f;
    uint32 r = a.u + 0x7fffu + ((a.u >> 16) & 1u);
    return (ushort)(r >> 16);
}

// ---- swizzled [kq][8b] f4 activation stage: conflict-free writes, broadcast reads ----
__device__ __forceinline__ void stage8(const float* __restrict__ src, float* __restrict__ st,
                                       int tid) {
    f4* d = (f4*)st;
    const f4* s = (const f4*)src;
    for (int idx = tid; idx < 1024; idx += 256) {
        int b = idx >> 7, kq = idx & 127;
        d[kq * 8 + (b ^ (kq & 7))] = s[idx];
    }
}
// ---- swizzled [kq][32b] stage for attn/gi (full batch) ----
__device__ __forceinline__ void stage_b32(const float* __restrict__ src, float* __restrict__ st,
                                          int tid, int nthr) {
    f4* d = (f4*)st;
    const f4* s = (const f4*)src;
    for (int idx = tid; idx < 4096; idx += nthr) {
        int b = idx >> 7, kq = idx & 127;
        d[kq * 32 + (b ^ (kq & 31))] = s[idx];
    }
}
__device__ __forceinline__ f4 ldb32(const float* __restrict__ st, int kq, int b) {
    return ((const f4*)st)[kq * 32 + (b ^ (kq & 31))];
}

// ---------------- fp32 -> bf16 row-major convert ----------------
__global__ void cvt_bf16_kernel(const float* __restrict__ src, ushort* __restrict__ dst, int n4) {
    int i = blockIdx.x * 256 + threadIdx.x;
    if (i < n4) {
        f4 v = ((const f4*)src)[i];
        ushort4 o;
        o.x = f2bf(v.x); o.y = f2bf(v.y); o.z = f2bf(v.z); o.w = f2bf(v.w);
        ((ushort4*)dst)[i] = o;
    }
}

// ---------------- fp32 [R][C] -> bf16 transposed [C][R] ----------------
__global__ void transcvt_kernel(const float* __restrict__ in, ushort* __restrict__ out,
                                int R, int C) {
    __shared__ float tile[32][33];
    int r0 = blockIdx.x * 32, c0 = blockIdx.y * 32;
    int tx = threadIdx.x & 31, ty = threadIdx.x >> 5;
#pragma unroll
    for (int k = 0; k < 4; ++k)
        tile[ty + k * 8][tx] = in[(size_t)(r0 + ty + k * 8) * C + c0 + tx];
    __syncthreads();
#pragma unroll
    for (int k = 0; k < 4; ++k) {
        int c = c0 + ty + k * 8;
        out[(size_t)c * R + r0 + tx] = f2bf(tile[tx][ty + k * 8]);
    }
}

// ---------------- 32x32 tiled transpose (Wk only, fp32) ----------------
__global__ void transpose_kernel(const float* __restrict__ in, float* __restrict__ out,
                                 int R, int C, int ldin) {
    __shared__ float tile[32][33];
    int r0 = blockIdx.x * 32, c0 = blockIdx.y * 32;
    int tx = threadIdx.x & 31, ty = threadIdx.x >> 5;
#pragma unroll
    for (int k = 0; k < 4; ++k) {
        int r = r0 + ty + k * 8;
        tile[ty + k * 8][tx] = in[(size_t)r * ldin + c0 + tx];
    }
    __syncthreads();
#pragma unroll
    for (int k = 0; k < 4; ++k) {
        int c = c0 + ty + k * 8;
        out[(size_t)c * R + r0 + tx] = tile[tx][ty + k * 8];
    }
}

// ---------------- kpT[b][c][t] = sum_k enc[b*T+t][k] * WkT[k][c] ----------------
__global__ void __launch_bounds__(256) kproj_gemm_kernel(const float* __restrict__ A,
                                                         const float* __restrict__ Bt,
                                                         float* __restrict__ kpT) {
    __shared__ float As[64][68];
    __shared__ float Bs[64][64];
    int r0 = blockIdx.x * 64, c0 = blockIdx.y * 64;
    int tid = threadIdx.x;
    int tx = tid & 15, ty = tid >> 4;
    float acc[4][4] = {};
    for (int k0 = 0; k0 < 512; k0 += 64) {
#pragma unroll
        for (int i = 0; i < 4; ++i) {
            int row = i * 16 + ty, col = tx * 4;
            f4 av = *(const f4*)(A + (size_t)(r0 + row) * 512 + k0 + col);
            As[row][col] = av.x; As[row][col + 1] = av.y; As[row][col + 2] = av.z; As[row][col + 3] = av.w;
            f4 bv = *(const f4*)(Bt + (size_t)(k0 + row) * 512 + c0 + col);
            *(f4*)&Bs[row][col] = bv;
        }
        __syncthreads();
#pragma unroll 8
        for (int kk = 0; kk < 64; ++kk) {
            float a[4];
#pragma unroll
            for (int i = 0; i < 4; ++i) a[i] = As[ty * 4 + i][kk];
            f4 bv = *(const f4*)&Bs[kk][tx * 4];
#pragma unroll
            for (int i = 0; i < 4; ++i) {
                acc[i][0] += a[i] * bv.x; acc[i][1] += a[i] * bv.y;
                acc[i][2] += a[i] * bv.z; acc[i][3] += a[i] * bv.w;
            }
        }
        __syncthreads();
    }
#pragma unroll
    for (int i = 0; i < 4; ++i) {
        int r = r0 + ty * 4 + i;
        int b = r >> 7, t = r & 127;
#pragma unroll
        for (int j = 0; j < 4; ++j) {
            int c = c0 + tx * 4 + j;
            kpT[((size_t)b * H + c) * T + t] = acc[i][j];
        }
    }
}

// ---------------- init ----------------
__global__ void __launch_bounds__(512) init_kernel(const float* __restrict__ hidden,
                                                   const float* __restrict__ emb_W,
                                                   const float* __restrict__ emb_b,
                                                   float* __restrict__ h0, float* __restrict__ h1,
                                                   float* __restrict__ inp) {
    int b = blockIdx.x, tid = threadIdx.x;
    h0[b * H + tid] = hidden[b * H + tid];
    h1[b * H + tid] = hidden[BH + b * H + tid];
    if (b == 0) {
        const f4* row = (const f4*)(emb_W + (size_t)tid * ODIM);
        float acc = emb_b[tid];
#pragma unroll 8
        for (int o = 0; o < 64; ++o) { f4 v = row[o]; acc += v.x + v.y + v.z + v.w; }
        for (int bb = 0; bb < B; ++bb) inp[bb * E + tid] = acc;
    }
}

// ---------------- attn1: qproj (64 x 8j, all b) + lin(prev) (32 x 8o, all b) ----------------
__global__ void __launch_bounds__(256) attn1_kernel(
    int nb_q, const float* __restrict__ h1cur, const float* __restrict__ Wq,
    float* __restrict__ q, const float* __restrict__ last_W, const float* __restrict__ last_b,
    const float* __restrict__ target_step, const int* __restrict__ mask_step,
    float* __restrict__ f, float* __restrict__ out_step) {
    __shared__ float sh[16384];
    int tid = threadIdx.x;
    stage_b32(h1cur, sh, tid, 256);
    __syncthreads();
    if ((int)blockIdx.x < nb_q) {
        int jg = blockIdx.x * 8 + (tid & 7), b = tid >> 3;
        const f4* w = (const f4*)(Wq + (size_t)jg * H);
        float acc = 0.f;
#pragma unroll 8
        for (int kq = 0; kq < 128; ++kq) acc += dot4(w[kq], ldb32(sh, kq, b));
        q[b * H + jg] = acc;
    } else {
        int og = (blockIdx.x - nb_q) * 8 + (tid & 7), b = tid >> 3;
        const f4* w = (const f4*)(last_W + (size_t)og * H);
        float acc = 0.f;
#pragma unroll 8
        for (int kq = 0; kq < 128; ++kq) acc += dot4(w[kq], ldb32(sh, kq, b));
        float lin = acc + last_b[og];
        float ff = mask_step[b] ? target_step[b * ODIM + og] : lin;
        f[b * ODIM + og] = ff;
        out_step[b * ODIM + og] = ff;
    }
}

// ---------------- attn2: scores partials (256 blk) + emb(prev) (32 blk) ----------------
__global__ void __launch_bounds__(256) attn2_kernel(
    const float* __restrict__ q, const float* __restrict__ kpT, const float* __restrict__ wv,
    float* __restrict__ spart, const float* __restrict__ f, const float* __restrict__ emb_W,
    const float* __restrict__ emb_b, float* __restrict__ inp) {
    __shared__ float sm[8704];
    int tid = threadIdx.x;
    if ((int)blockIdx.x < 256) {
        int b = blockIdx.x >> 3, js = blockIdx.x & 7;
        float* qs = sm;
        float* ws_ = sm + 64;
        float* part = sm + 128;
        if (tid < 64) {
            qs[tid] = q[b * H + js * 64 + tid];
            ws_[tid] = wv[js * 64 + tid];
        }
        __syncthreads();
        int t = tid & 127, jh = tid >> 7;
        const float* kp = kpT + ((size_t)b * H + js * 64 + jh * 32) * T + t;
        float sa = 0.f;
#pragma unroll 8
        for (int jj = 0; jj < 32; ++jj) {
            int j = jh * 32 + jj;
            sa += tanh_fast(qs[j] + kp[(size_t)jj * T]) * ws_[j];
        }
        part[tid] = sa;
        __syncthreads();
        if (tid < 128) spart[((size_t)b * 8 + js) * T + tid] = part[tid] + part[128 + tid];
    } else {
        float* st = sm;
        {
            f4* d = (f4*)st;
            const f4* s = (const f4*)f;
            for (int idx = tid; idx < 2048; idx += 256) {
                int b = idx >> 6, oq = idx & 63;
                d[oq * 32 + (b ^ (oq & 31))] = s[idx];
            }
        }
        __syncthreads();
        int eg = (blockIdx.x - 256) * 16 + (tid & 15), bq = tid >> 4;
        const f4* w = (const f4*)(emb_W + (size_t)eg * ODIM);
        float a0 = 0.f, a1 = 0.f;
#pragma unroll 4
        for (int oq = 0; oq < 64; ++oq) {
            f4 wv_ = w[oq];
            a0 += dot4(wv_, ((const f4*)st)[oq * 32 + (bq ^ (oq & 31))]);
            a1 += dot4(wv_, ((const f4*)st)[oq * 32 + ((bq + 16) ^ (oq & 31))]);
        }
        float eb = emb_b[eg];
        inp[bq * E + eg] = a0 + eb;
        inp[(bq + 16) * E + eg] = a1 + eb;
    }
}

// ---------------- attn3: softmax + ctx (256 blk: 32b x 8cs) ----------------
__global__ void __launch_bounds__(256) attn3_kernel(
    const float* __restrict__ spart, const float* __restrict__ enc,
    float* __restrict__ ctx, float* __restrict__ attn_out) {
    __shared__ float sw[T];
    __shared__ float red[4];
    __shared__ float part[256];
    int tid = threadIdx.x;
    int b = blockIdx.x >> 3, cs = blockIdx.x & 7;
    float sv = 0.f;
    if (tid < 128) {
        const float* sp = spart + (size_t)b * 8 * T + tid;
#pragma unroll
        for (int js = 0; js < 8; ++js) sv += sp[js * T];
        float m = sv;
        for (int off = 32; off; off >>= 1) m = fmaxf(m, __shfl_xor(m, off));
        if ((tid & 63) == 0) red[tid >> 6] = m;
    }
    __syncthreads();
    if (tid < 128) {
        float M = fmaxf(red[0], red[1]);
        float e = __expf(sv - M);
        sw[tid] = e;
        float s = e;
        for (int off = 32; off; off >>= 1) s += __shfl_xor(s, off);
        if ((tid & 63) == 0) red[2 + (tid >> 6)] = s;
    }
    __syncthreads();
    if (tid < 128) {
        float w = sw[tid] / (red[2] + red[3]);
        sw[tid] = w;
        if (cs == 0) attn_out[(size_t)b * T + tid] = w;
    }
    __syncthreads();
    int c = tid & 63, tq = tid >> 6;
    int cg = cs * 64 + c;
    const float* ep = enc + ((size_t)b * T + tq * 32) * H + cg;
    float acc = 0.f;
#pragma unroll 8
    for (int t2 = 0; t2 < 32; ++t2) acc += sw[tq * 32 + t2] * ep[(size_t)t2 * H];
    part[tid] = acc;
    __syncthreads();
    if (tid < 64) ctx[(size_t)b * H + cg] = part[tid] + part[64 + tid] + part[128 + tid] + part[192 + tid];
}

// ---------------- gi (bf16 W row-major): 96 blk gi_ctx (+bi0) | 96 blk gi_emb[i] ----------------
__global__ void __launch_bounds__(256) gi_kernel(
    const float* __restrict__ ctx, const float* __restrict__ inp,
    const ushort* __restrict__ Wi0bf, const float* __restrict__ bi0,
    float* __restrict__ gi_ctx, float* __restrict__ gi_emb_i) {
    __shared__ float sh[16384];
    int tid = threadIdx.x;
    bool isC = (int)blockIdx.x < 96;
    int lb = isC ? blockIdx.x : blockIdx.x - 96;
    stage_b32(isC ? ctx : inp, sh, tid, 256);
    __syncthreads();
    int cg = lb * 16 + (tid & 15), bq = tid >> 4;
    const uint4* w = (const uint4*)(Wi0bf + (size_t)cg * 1024 + (isC ? 0 : 512));
    float a0 = 0.f, a1 = 0.f;
#pragma unroll 4
    for (int it = 0; it < 64; ++it) {
        uint4 wv = w[it];
        f4 hA0 = ldb32(sh, it * 2, bq), hB0 = ldb32(sh, it * 2 + 1, bq);
        f4 hA1 = ldb32(sh, it * 2, bq + 16), hB1 = ldb32(sh, it * 2 + 1, bq + 16);
        a0 += dot8bf(wv, hA0, hB0);
        a1 += dot8bf(wv, hA1, hB1);
    }
    float bias = isC ? bi0[cg] : 0.f;
    float* dst = isC ? gi_ctx : gi_emb_i;
    dst[(size_t)bq * G3 + cg] = a0 + bias;
    dst[(size_t)(bq + 16) * G3 + cg] = a1 + bias;
}

// ---------------- fused dual GRU cell: transposed bf16 weights, j-fast coalesced lanes ----------------
// l0: blocks [0,nb0=128): jc = bid&31 (16 j), bg = bid>>5 (8 b); threads 16j x 16ks
// l1: blocks [nb0,nb0+128): jc = lb&31 (16 j), bg = lb>>5 (8 b); threads 16j x 8ks x 2m
__global__ void __launch_bounds__(256) cell_kernel(
    int nb0, const float* __restrict__ h0_src, float* __restrict__ h0_dst,
    const float* __restrict__ h1_src, float* __restrict__ h1_dst,
    const float* __restrict__ gi_emb_t, const float* __restrict__ gi_ctx,
    const ushort* __restrict__ Wh0T, const float* __restrict__ bh0,
    const ushort* __restrict__ Wi1T, const float* __restrict__ bi1,
    const ushort* __restrict__ Wh1T, const float* __restrict__ bh1) {
    __shared__ __align__(16) float sh[14592];  // 58.4 KB
    int tid = threadIdx.x;
    if ((int)blockIdx.x < nb0) {
        int jc = blockIdx.x & 31, bg = blockIdx.x >> 5;
        int j0 = jc * 16, b0 = bg * 8;
        stage8(h0_src + (size_t)b0 * H, sh, tid);
        __syncthreads();
        int j = tid & 15, ks = tid >> 4;  // 16 ks x 32 k
        int jg = j0 + j;
        float a0[8] = {}, a1[8] = {}, a2[8] = {};
        for (int kq = ks * 8; kq < ks * 8 + 8; ++kq) {
            f4 hv[8];
#pragma unroll
            for (int b = 0; b < 8; ++b) hv[b] = ((const f4*)sh)[kq * 8 + (b ^ (kq & 7))];
#pragma unroll
            for (int ki = 0; ki < 4; ++ki) {
                int k = kq * 4 + ki;
                const ushort* wr = Wh0T + (size_t)k * G3 + jg;
                float w0 = bfu(wr[0]), w1 = bfu(wr[512]), w2 = bfu(wr[1024]);
#pragma unroll
                for (int b = 0; b < 8; ++b) {
                    float h = ((const float*)&hv[b])[ki];
                    a0[b] = fmaf(w0, h, a0[b]);
                    a1[b] = fmaf(w1, h, a1[b]);
                    a2[b] = fmaf(w2, h, a2[b]);
                }
            }
        }
        float* part = sh + 4096;
        {
            float* pr = part + (ks * 16 + j) * 25;
#pragma unroll
            for (int b = 0; b < 8; ++b) { pr[b] = a0[b]; pr[8 + b] = a1[b]; pr[16 + b] = a2[b]; }
        }
        __syncthreads();
        if (tid < 128) {
            int fj = tid & 15, fb = tid >> 4;
            int jg2 = j0 + fj, bg2 = b0 + fb;
            float s0 = 0.f, s1 = 0.f, s2 = 0.f;
#pragma unroll
            for (int k2 = 0; k2 < 16; ++k2) {
                const float* p = part + (k2 * 16 + fj) * 25;
                s0 += p[fb]; s1 += p[8 + fb]; s2 += p[16 + fb];
            }
            const float* gc = gi_ctx + (size_t)bg2 * G3;
            const float* ge = gi_emb_t + (size_t)bg2 * G3;
            float r_ = sigmoidf_(gc[jg2] + ge[jg2] + s0 + bh0[jg2]);
            float z_ = sigmoidf_(gc[H + jg2] + ge[H + jg2] + s1 + bh0[H + jg2]);
            float n_ = tanh_fast(gc[2 * H + jg2] + ge[2 * H + jg2] + r_ * (s2 + bh0[2 * H + jg2]));
            int kq = jg2 >> 2;
            f4 hp = ((const f4*)sh)[kq * 8 + (fb ^ (kq & 7))];
            float hprev = ((const float*)&hp)[jg2 & 3];
            h0_dst[(size_t)bg2 * H + jg2] = (1.f - z_) * n_ + z_ * hprev;
        }
    } else {
        int lb = blockIdx.x - nb0;
        int jc = lb & 31, bg = lb >> 5;
        int j0 = jc * 16, b0 = bg * 8;
        stage8(h0_src + (size_t)b0 * H, sh, tid);         // x = y0(t-1)
        stage8(h1_src + (size_t)b0 * H, sh + 4096, tid);  // h1
        __syncthreads();
        int j = tid & 15, ks = (tid >> 4) & 7, m = tid >> 7;  // 8 ks x 64 k, 2 m
        int jg = j0 + j;
        const ushort* WT = m ? Wh1T : Wi1T;
        const float* stm = m ? sh + 4096 : sh;
        float a0[8] = {}, a1[8] = {}, a2[8] = {};
        for (int kq = ks * 16; kq < ks * 16 + 16; ++kq) {
            f4 hv[8];
#pragma unroll
            for (int b = 0; b < 8; ++b) hv[b] = ((const f4*)stm)[kq * 8 + (b ^ (kq & 7))];
#pragma unroll
            for (int ki = 0; ki < 4; ++ki) {
                int k = kq * 4 + ki;
                const ushort* wr = WT + (size_t)k * G3 + jg;
                float w0 = bfu(wr[0]), w1 = bfu(wr[512]), w2 = bfu(wr[1024]);
#pragma unroll
                for (int b = 0; b < 8; ++b) {
                    float h = ((const float*)&hv[b])[ki];
                    a0[b] = fmaf(w0, h, a0[b]);
                    a1[b] = fmaf(w1, h, a1[b]);
                    a2[b] = fmaf(w2, h, a2[b]);
                }
            }
        }
        float* part = sh + 8192;
        {
            float* pr = part + ((m * 8 + ks) * 16 + j) * 25;
#pragma unroll
            for (int b = 0; b < 8; ++b) { pr[b] = a0[b]; pr[8 + b] = a1[b]; pr[16 + b] = a2[b]; }
        }
        __syncthreads();
        if (tid < 128) {
            int fj = tid & 15, fb = tid >> 4;
            int jg2 = j0 + fj, bg2 = b0 + fb;
            float i0 = 0.f, i1 = 0.f, i2 = 0.f, g0 = 0.f, g1 = 0.f, g2 = 0.f;
#pragma unroll
            for (int k2 = 0; k2 < 8; ++k2) {
                const float* pi = part + (k2 * 16 + fj) * 25;
                const float* ph = part + ((128 + k2 * 16 + fj)) * 25;
                i0 += pi[fb]; i1 += pi[8 + fb]; i2 += pi[16 + fb];
                g0 += ph[fb]; g1 += ph[8 + fb]; g2 += ph[16 + fb];
            }
            float r_ = sigmoidf_(i0 + bi1[jg2] + g0 + bh1[jg2]);
            float z_ = sigmoidf_(i1 + bi1[H + jg2] + g1 + bh1[H + jg2]);
            float n_ = tanh_fast(i2 + bi1[2 * H + jg2] + r_ * (g2 + bh1[2 * H + jg2]));
            int kq = jg2 >> 2;
            f4 hp = ((const f4*)(sh + 4096))[kq * 8 + (fb ^ (kq & 7))];
            float hprev = ((const float*)&hp)[jg2 & 3];
            h1_dst[(size_t)bg2 * H + jg2] = (1.f - z_) * n_ + z_ * hprev;
        }
    }
}

__global__ void copy_hidden_kernel(const float* __restrict__ h0, const float* __restrict__ h1,
                                   float* __restrict__ dst) {
    int i = blockIdx.x * 256 + threadIdx.x;
    dst[i] = h0[i];
    dst[BH + i] = h1[i];
}

extern "C" void kernel_launch(void* const* d_in, const int* in_sizes, int n_in,
                              void* d_out_v, int out_size, void* d_ws, size_t ws_size,
                              hipStream_t stream) {
    const float* enc = (const float*)d_in[0];
    const float* hidden = (const float*)d_in[1];
    const float* target = (const float*)d_in[2];
    const float* Wq = (const float*)d_in[3];
    const float* Wk = (const float*)d_in[4];
    const float* wv = (const float*)d_in[5];
    const float* emb_W = (const float*)d_in[6];
    const float* emb_b = (const float*)d_in[7];
    const float* Wi0 = (const float*)d_in[8];
    const float* Wh0 = (const float*)d_in[9];
    const float* bi0 = (const float*)d_in[10];
    const float* bh0 = (const float*)d_in[11];
    const float* Wi1 = (const float*)d_in[12];
    const float* Wh1 = (const float*)d_in[13];
    const float* bi1 = (const float*)d_in[14];
    const float* bh1 = (const float*)d_in[15];
    const float* last_W = (const float*)d_in[16];
    const float* last_b = (const float*)d_in[17];
    const int* tmask = (const int*)d_in[18];

    float* out = (float*)d_out_v;
    float* out_hidden = out + (size_t)STEPS * B * ODIM;
    float* out_attn = out_hidden + (size_t)2 * BH;

    float* ws = (float*)d_ws;
    float* kpT = ws;                      // 2,097,152
    float* WkT = kpT + 2097152;           // 262,144
    float* gi_emb = WkT + 262144;         // 786,432
    float* gi_ctx = gi_emb + 786432;      // 49,152
    float* h0buf = gi_ctx + 49152;        // 32,768 (2x)
    float* h1buf = h0buf + 32768;         // 32,768 (2x)
    float* qbuf = h1buf + 32768;          // 16,384
    float* ctxbuf = qbuf + 16384;         // 16,384
    float* fbuf = ctxbuf + 16384;         // 8,192
    float* inpbuf = fbuf + 8192;          // 16,384
    float* spart = inpbuf + 16384;        // 32,768
    ushort* Wi0bf = (ushort*)(spart + 32768);  // 1,572,864 ushorts (row-major)
    ushort* Wh0T = Wi0bf + 1572864;            // 786,432 (transposed [k][G3])
    ushort* Wi1T = Wh0T + 786432;              // 786,432
    ushort* Wh1T = Wi1T + 786432;              // 786,432

    // weight conversions
    cvt_bf16_kernel<<<1536, 256, 0, stream>>>(Wi0, Wi0bf, 393216);
    transcvt_kernel<<<dim3(48, 16), 256, 0, stream>>>(Wh0, Wh0T, G3, H);
    transcvt_kernel<<<dim3(48, 16), 256, 0, stream>>>(Wi1, Wi1T, G3, H);
    transcvt_kernel<<<dim3(48, 16), 256, 0, stream>>>(Wh1, Wh1T, G3, H);

    transpose_kernel<<<dim3(16, 16), 256, 0, stream>>>(Wk, WkT, 512, 512, 512);
    kproj_gemm_kernel<<<dim3(64, 8), 256, 0, stream>>>(enc, WkT, kpT);
    init_kernel<<<B, 512, 0, stream>>>(hidden, emb_W, emb_b, h0buf, h1buf, inpbuf);

    int p0 = 0, p1 = 0;
    for (int i = 0; i < STEPS; ++i) {
        int im1 = (i > 0) ? i - 1 : 0;
        const float* h1cur = h1buf + (size_t)p1 * BH;
        attn1_kernel<<<(i > 0) ? 96 : 64, 256, 0, stream>>>(
            64, h1cur, Wq, qbuf, last_W, last_b, target + (size_t)im1 * B * ODIM,
            tmask + im1 * B, fbuf, out + (size_t)im1 * B * ODIM);
        attn2_kernel<<<(i > 0) ? 288 : 256, 256, 0, stream>>>(qbuf, kpT, wv, spart, fbuf,
                                                              emb_W, emb_b, inpbuf);
        attn3_kernel<<<256, 256, 0, stream>>>(spart, enc, ctxbuf, out_attn + (size_t)i * B * T);
        gi_kernel<<<192, 256, 0, stream>>>(ctxbuf, inpbuf, Wi0bf, bi0, gi_ctx,
                                           gi_emb + (size_t)i * B * G3);
        for (int t = 0; t <= i + 1; ++t) {
            int nb0 = (t <= i) ? 128 : 0;
            int nb1 = (t >= 1) ? 128 : 0;
            int tge = (t <= i) ? t : 0;
            cell_kernel<<<nb0 + nb1, 256, 0, stream>>>(
                nb0, h0buf + (size_t)p0 * BH, h0buf + (size_t)(p0 ^ 1) * BH,
                h1buf + (size_t)p1 * BH, h1buf + (size_t)(p1 ^ 1) * BH,
                gi_emb + (size_t)tge * B * G3, gi_ctx, Wh0T, bh0, Wi1T, bi1, Wh1T, bh1);
            if (nb0) p0 ^= 1;
            if (nb1) p1 ^= 1;
        }
    }
    // final lin (step 15)
    attn1_kernel<<<32, 256, 0, stream>>>(0, h1buf + (size_t)p1 * BH, Wq, qbuf, last_W, last_b,
                                         target + (size_t)15 * B * ODIM, tmask + 15 * B, fbuf,
                                         out + (size_t)15 * B * ODIM);
    copy_hidden_kernel<<<64, 256, 0, stream>>>(h0buf + (size_t)p0 * BH, h1buf + (size_t)p1 * BH,
                                               out_hidden);
}

// Round 10
// 2508.104 us; speedup vs baseline: 2.2717x; 2.2717x over previous
//
#include <hip/hip_runtime.h>
#include <math.h>

#define B 32
#define T 128
#define H 512
#define E 512
#define ODIM 256
#define STEPS 16
#define G3 1536
#define BH (B * H)

typedef float4 f4;
typedef unsigned int uint32;
typedef unsigned short ushort;

__device__ __forceinline__ float sigmoidf_(float x) { return 1.0f / (1.0f + __expf(-x)); }
__device__ __forceinline__ float tanh_fast(float x) {
    float t = __expf(-2.0f * fabsf(x));
    float r = (1.0f - t) / (1.0f + t);
    return __builtin_copysignf(r, x);
}
__device__ __forceinline__ float dot4(const f4 a, const f4 b) {
    return fmaf(a.x, b.x, fmaf(a.y, b.y, fmaf(a.z, b.z, a.w * b.w)));
}
__device__ __forceinline__ void bf2x(uint32 v, float& lo, float& hi) {
    union { uint32 u; float f; } a, b;
    a.u = v << 16; b.u = v & 0xffff0000u;
    lo = a.f; hi = b.f;
}
__device__ __forceinline__ float dot8bf(uint4 wv, const f4 hA, const f4 hB) {
    float w0, w1, w2, w3, w4, w5, w6, w7;
    bf2x(wv.x, w0, w1); bf2x(wv.y, w2, w3); bf2x(wv.z, w4, w5); bf2x(wv.w, w6, w7);
    float s = fmaf(w0, hA.x, w1 * hA.y);
    s = fmaf(w2, hA.z, s); s = fmaf(w3, hA.w, s);
    s = fmaf(w4, hB.x, s); s = fmaf(w5, hB.y, s);
    s = fmaf(w6, hB.z, s); s = fmaf(w7, hB.w, s);
    return s;
}
__device__ __forceinline__ ushort f2bf(float f) {
    union { float f; uint32 u; } a; a.f = f;
    uint32 r = a.u + 0x7fffu + ((a.u >> 16) & 1u);
    return (ushort)(r >> 16);
}

// ---- 4-batch act stage: f4 slot A0(kq,b) = kq*4 + (kq>>3) + b  (pad breaks 32-word aliasing) ----
#define A0(kq, b) ((kq) * 4 + ((kq) >> 3) + (b))
#define ST4_SZ 544  // > 127*4+15+3
__device__ __forceinline__ void stage4(const float* __restrict__ src, float* __restrict__ st,
                                       int tid) {
    f4* d = (f4*)st;
    const f4* s = (const f4*)src;
    for (int idx = tid; idx < 512; idx += 256) {
        int b = idx >> 7, kq = idx & 127;
        d[A0(kq, b)] = s[idx];
    }
}

// ---- full-batch swizzled stage (attn/gi kernels) ----
__device__ __forceinline__ void stage_b32(const float* __restrict__ src, float* __restrict__ st,
                                          int tid, int nthr) {
    f4* d = (f4*)st;
    const f4* s = (const f4*)src;
    for (int idx = tid; idx < 4096; idx += nthr) {
        int b = idx >> 7, kq = idx & 127;
        d[kq * 32 + (b ^ (kq & 31))] = s[idx];
    }
}
__device__ __forceinline__ f4 ldb32(const float* __restrict__ st, int kq, int b) {
    return ((const f4*)st)[kq * 32 + (b ^ (kq & 31))];
}

// ---------------- fp32 -> bf16 row-major convert ----------------
__global__ void cvt_bf16_kernel(const float* __restrict__ src, ushort* __restrict__ dst, int n4) {
    int i = blockIdx.x * 256 + threadIdx.x;
    if (i < n4) {
        f4 v = ((const f4*)src)[i];
        ushort4 o;
        o.x = f2bf(v.x); o.y = f2bf(v.y); o.z = f2bf(v.z); o.w = f2bf(v.w);
        ((ushort4*)dst)[i] = o;
    }
}

// ---------------- 32x32 tiled transpose (Wk only, fp32) ----------------
__global__ void transpose_kernel(const float* __restrict__ in, float* __restrict__ out,
                                 int R, int C, int ldin) {
    __shared__ float tile[32][33];
    int r0 = blockIdx.x * 32, c0 = blockIdx.y * 32;
    int tx = threadIdx.x & 31, ty = threadIdx.x >> 5;
#pragma unroll
    for (int k = 0; k < 4; ++k) {
        int r = r0 + ty + k * 8;
        tile[ty + k * 8][tx] = in[(size_t)r * ldin + c0 + tx];
    }
    __syncthreads();
#pragma unroll
    for (int k = 0; k < 4; ++k) {
        int c = c0 + ty + k * 8;
        out[(size_t)c * R + r0 + tx] = tile[tx][ty + k * 8];
    }
}

// ---------------- kpT[b][c][t] = sum_k enc[b*T+t][k] * WkT[k][c] ----------------
__global__ void __launch_bounds__(256) kproj_gemm_kernel(const float* __restrict__ A,
                                                         const float* __restrict__ Bt,
                                                         float* __restrict__ kpT) {
    __shared__ float As[64][68];
    __shared__ float Bs[64][64];
    int r0 = blockIdx.x * 64, c0 = blockIdx.y * 64;
    int tid = threadIdx.x;
    int tx = tid & 15, ty = tid >> 4;
    float acc[4][4] = {};
    for (int k0 = 0; k0 < 512; k0 += 64) {
#pragma unroll
        for (int i = 0; i < 4; ++i) {
            int row = i * 16 + ty, col = tx * 4;
            f4 av = *(const f4*)(A + (size_t)(r0 + row) * 512 + k0 + col);
            As[row][col] = av.x; As[row][col + 1] = av.y; As[row][col + 2] = av.z; As[row][col + 3] = av.w;
            f4 bv = *(const f4*)(Bt + (size_t)(k0 + row) * 512 + c0 + col);
            *(f4*)&Bs[row][col] = bv;
        }
        __syncthreads();
#pragma unroll 8
        for (int kk = 0; kk < 64; ++kk) {
            float a[4];
#pragma unroll
            for (int i = 0; i < 4; ++i) a[i] = As[ty * 4 + i][kk];
            f4 bv = *(const f4*)&Bs[kk][tx * 4];
#pragma unroll
            for (int i = 0; i < 4; ++i) {
                acc[i][0] += a[i] * bv.x; acc[i][1] += a[i] * bv.y;
                acc[i][2] += a[i] * bv.z; acc[i][3] += a[i] * bv.w;
            }
        }
        __syncthreads();
    }
#pragma unroll
    for (int i = 0; i < 4; ++i) {
        int r = r0 + ty * 4 + i;
        int b = r >> 7, t = r & 127;
#pragma unroll
        for (int j = 0; j < 4; ++j) {
            int c = c0 + tx * 4 + j;
            kpT[((size_t)b * H + c) * T + t] = acc[i][j];
        }
    }
}

// ---------------- init ----------------
__global__ void __launch_bounds__(512) init_kernel(const float* __restrict__ hidden,
                                                   const float* __restrict__ emb_W,
                                                   const float* __restrict__ emb_b,
                                                   float* __restrict__ h0, float* __restrict__ h1,
                                                   float* __restrict__ inp) {
    int b = blockIdx.x, tid = threadIdx.x;
    h0[b * H + tid] = hidden[b * H + tid];
    h1[b * H + tid] = hidden[BH + b * H + tid];
    if (b == 0) {
        const f4* row = (const f4*)(emb_W + (size_t)tid * ODIM);
        float acc = emb_b[tid];
#pragma unroll 8
        for (int o = 0; o < 64; ++o) { f4 v = row[o]; acc += v.x + v.y + v.z + v.w; }
        for (int bb = 0; bb < B; ++bb) inp[bb * E + tid] = acc;
    }
}

// ---------------- attn1: qproj (64 x 8j, all b) + lin(prev) (32 x 8o, all b) ----------------
__global__ void __launch_bounds__(256) attn1_kernel(
    int nb_q, const float* __restrict__ h1cur, const float* __restrict__ Wq,
    float* __restrict__ q, const float* __restrict__ last_W, const float* __restrict__ last_b,
    const float* __restrict__ target_step, const int* __restrict__ mask_step,
    float* __restrict__ f, float* __restrict__ out_step) {
    __shared__ float sh[16384];
    int tid = threadIdx.x;
    stage_b32(h1cur, sh, tid, 256);
    __syncthreads();
    if ((int)blockIdx.x < nb_q) {
        int jg = blockIdx.x * 8 + (tid & 7), b = tid >> 3;
        const f4* w = (const f4*)(Wq + (size_t)jg * H);
        float acc = 0.f;
#pragma unroll 8
        for (int kq = 0; kq < 128; ++kq) acc += dot4(w[kq], ldb32(sh, kq, b));
        q[b * H + jg] = acc;
    } else {
        int og = (blockIdx.x - nb_q) * 8 + (tid & 7), b = tid >> 3;
        const f4* w = (const f4*)(last_W + (size_t)og * H);
        float acc = 0.f;
#pragma unroll 8
        for (int kq = 0; kq < 128; ++kq) acc += dot4(w[kq], ldb32(sh, kq, b));
        float lin = acc + last_b[og];
        float ff = mask_step[b] ? target_step[b * ODIM + og] : lin;
        f[b * ODIM + og] = ff;
        out_step[b * ODIM + og] = ff;
    }
}

// ---------------- attn2: scores partials (256 blk) + emb(prev) (32 blk) ----------------
__global__ void __launch_bounds__(256) attn2_kernel(
    const float* __restrict__ q, const float* __restrict__ kpT, const float* __restrict__ wv,
    float* __restrict__ spart, const float* __restrict__ f, const float* __restrict__ emb_W,
    const float* __restrict__ emb_b, float* __restrict__ inp) {
    __shared__ float sm[8704];
    int tid = threadIdx.x;
    if ((int)blockIdx.x < 256) {
        int b = blockIdx.x >> 3, js = blockIdx.x & 7;
        float* qs = sm;
        float* ws_ = sm + 64;
        float* part = sm + 128;
        if (tid < 64) {
            qs[tid] = q[b * H + js * 64 + tid];
            ws_[tid] = wv[js * 64 + tid];
        }
        __syncthreads();
        int t = tid & 127, jh = tid >> 7;
        const float* kp = kpT + ((size_t)b * H + js * 64 + jh * 32) * T + t;
        float sa = 0.f;
#pragma unroll 8
        for (int jj = 0; jj < 32; ++jj) {
            int j = jh * 32 + jj;
            sa += tanh_fast(qs[j] + kp[(size_t)jj * T]) * ws_[j];
        }
        part[tid] = sa;
        __syncthreads();
        if (tid < 128) spart[((size_t)b * 8 + js) * T + tid] = part[tid] + part[128 + tid];
    } else {
        float* st = sm;
        {
            f4* d = (f4*)st;
            const f4* s = (const f4*)f;
            for (int idx = tid; idx < 2048; idx += 256) {
                int b = idx >> 6, oq = idx & 63;
                d[oq * 32 + (b ^ (oq & 31))] = s[idx];
            }
        }
        __syncthreads();
        int eg = (blockIdx.x - 256) * 16 + (tid & 15), bq = tid >> 4;
        const f4* w = (const f4*)(emb_W + (size_t)eg * ODIM);
        float a0 = 0.f, a1 = 0.f;
#pragma unroll 4
        for (int oq = 0; oq < 64; ++oq) {
            f4 wv_ = w[oq];
            a0 += dot4(wv_, ((const f4*)st)[oq * 32 + (bq ^ (oq & 31))]);
            a1 += dot4(wv_, ((const f4*)st)[oq * 32 + ((bq + 16) ^ (oq & 31))]);
        }
        float eb = emb_b[eg];
        inp[bq * E + eg] = a0 + eb;
        inp[(bq + 16) * E + eg] = a1 + eb;
    }
}

// ---------------- attn3: softmax + ctx (256 blk: 32b x 8cs) ----------------
__global__ void __launch_bounds__(256) attn3_kernel(
    const float* __restrict__ spart, const float* __restrict__ enc,
    float* __restrict__ ctx, float* __restrict__ attn_out) {
    __shared__ float sw[T];
    __shared__ float red[4];
    __shared__ float part[256];
    int tid = threadIdx.x;
    int b = blockIdx.x >> 3, cs = blockIdx.x & 7;
    float sv = 0.f;
    if (tid < 128) {
        const float* sp = spart + (size_t)b * 8 * T + tid;
#pragma unroll
        for (int js = 0; js < 8; ++js) sv += sp[js * T];
        float m = sv;
        for (int off = 32; off; off >>= 1) m = fmaxf(m, __shfl_xor(m, off));
        if ((tid & 63) == 0) red[tid >> 6] = m;
    }
    __syncthreads();
    if (tid < 128) {
        float M = fmaxf(red[0], red[1]);
        float e = __expf(sv - M);
        sw[tid] = e;
        float s = e;
        for (int off = 32; off; off >>= 1) s += __shfl_xor(s, off);
        if ((tid & 63) == 0) red[2 + (tid >> 6)] = s;
    }
    __syncthreads();
    if (tid < 128) {
        float w = sw[tid] / (red[2] + red[3]);
        sw[tid] = w;
        if (cs == 0) attn_out[(size_t)b * T + tid] = w;
    }
    __syncthreads();
    int c = tid & 63, tq = tid >> 6;
    int cg = cs * 64 + c;
    const float* ep = enc + ((size_t)b * T + tq * 32) * H + cg;
    float acc = 0.f;
#pragma unroll 8
    for (int t2 = 0; t2 < 32; ++t2) acc += sw[tq * 32 + t2] * ep[(size_t)t2 * H];
    part[tid] = acc;
    __syncthreads();
    if (tid < 64) ctx[(size_t)b * H + cg] = part[tid] + part[64 + tid] + part[128 + tid] + part[192 + tid];
}

// ---------------- gi (bf16 W row-major): 96 blk gi_ctx (+bi0) | 96 blk gi_emb[i] ----------------
__global__ void __launch_bounds__(256) gi_kernel(
    const float* __restrict__ ctx, const float* __restrict__ inp,
    const ushort* __restrict__ Wi0bf, const float* __restrict__ bi0,
    float* __restrict__ gi_ctx, float* __restrict__ gi_emb_i) {
    __shared__ float sh[16384];
    int tid = threadIdx.x;
    bool isC = (int)blockIdx.x < 96;
    int lb = isC ? blockIdx.x : blockIdx.x - 96;
    stage_b32(isC ? ctx : inp, sh, tid, 256);
    __syncthreads();
    int cg = lb * 16 + (tid & 15), bq = tid >> 4;
    const uint4* w = (const uint4*)(Wi0bf + (size_t)cg * 1024 + (isC ? 0 : 512));
    float a0 = 0.f, a1 = 0.f;
#pragma unroll 4
    for (int it = 0; it < 64; ++it) {
        uint4 wv = w[it];
        f4 hA0 = ldb32(sh, it * 2, bq), hB0 = ldb32(sh, it * 2 + 1, bq);
        f4 hA1 = ldb32(sh, it * 2, bq + 16), hB1 = ldb32(sh, it * 2 + 1, bq + 16);
        a0 += dot8bf(wv, hA0, hB0);
        a1 += dot8bf(wv, hA1, hB1);
    }
    float bias = isC ? bi0[cg] : 0.f;
    float* dst = isC ? gi_ctx : gi_emb_i;
    dst[(size_t)bq * G3 + cg] = a0 + bias;
    dst[(size_t)(bq + 16) * G3 + cg] = a1 + bias;
}

// ---------------- fused dual GRU cell: row-major bf16, k-contiguous uint4, k-split reduce ----------------
// l0: blocks [0,nb0=256): jc=bid&31 (16 j), bg=bid>>5 (4 b). threads: j=tid&15, ks=tid>>4 (16 x 32k)
// l1: blocks [nb0,+256): same geometry; threads: j=tid&15, ks=(tid>>4)&7 (8 x 64k), m=tid>>7
__global__ void __launch_bounds__(256) cell_kernel(
    int nb0, const float* __restrict__ h0_src, float* __restrict__ h0_dst,
    const float* __restrict__ h1_src, float* __restrict__ h1_dst,
    const float* __restrict__ gi_emb_t, const float* __restrict__ gi_ctx,
    const ushort* __restrict__ Wh0bf, const float* __restrict__ bh0,
    const ushort* __restrict__ Wi1bf, const float* __restrict__ bi1,
    const ushort* __restrict__ Wh1bf, const float* __restrict__ bh1) {
    __shared__ __align__(16) float sh[7936];  // 31.75 KB max (l1)
    int tid = threadIdx.x;
    if ((int)blockIdx.x < nb0) {
        int jc = blockIdx.x & 31, bg = blockIdx.x >> 5;
        int j0 = jc * 16, b0 = bg * 4;
        stage4(h0_src + (size_t)b0 * H, sh, tid);
        __syncthreads();
        int j = tid & 15, ks = tid >> 4, jg = j0 + j;
        const uint4* w0 = (const uint4*)(Wh0bf + (size_t)jg * 512) + ks * 4;
        const uint4* w1 = (const uint4*)(Wh0bf + (size_t)(512 + jg) * 512) + ks * 4;
        const uint4* w2 = (const uint4*)(Wh0bf + (size_t)(1024 + jg) * 512) + ks * 4;
        float a0[4] = {}, a1[4] = {}, a2[4] = {};
#pragma unroll
        for (int c = 0; c < 4; ++c) {
            uint4 u0 = w0[c], u1 = w1[c], u2 = w2[c];
            int kq = ks * 8 + c * 2;
#pragma unroll
            for (int b = 0; b < 4; ++b) {
                f4 hA = ((const f4*)sh)[A0(kq, b)];
                f4 hB = ((const f4*)sh)[A0(kq + 1, b)];
                a0[b] += dot8bf(u0, hA, hB);
                a1[b] += dot8bf(u1, hA, hB);
                a2[b] += dot8bf(u2, hA, hB);
            }
        }
        float* part = sh + ST4_SZ * 4;  // 2176 floats in
        {
            float* p = part + (size_t)tid * 13;
#pragma unroll
            for (int b = 0; b < 4; ++b) { p[b] = a0[b]; p[4 + b] = a1[b]; p[8 + b] = a2[b]; }
        }
        __syncthreads();
        if (tid < 64) {
            int fj = tid & 15, fb = tid >> 4;
            int jg2 = j0 + fj, bg2 = b0 + fb;
            float s0 = 0.f, s1 = 0.f, s2 = 0.f;
#pragma unroll
            for (int k2 = 0; k2 < 16; ++k2) {
                const float* p = part + (size_t)(k2 * 16 + fj) * 13;
                s0 += p[fb]; s1 += p[4 + fb]; s2 += p[8 + fb];
            }
            const float* gc = gi_ctx + (size_t)bg2 * G3;
            const float* ge = gi_emb_t + (size_t)bg2 * G3;
            float r_ = sigmoidf_(gc[jg2] + ge[jg2] + s0 + bh0[jg2]);
            float z_ = sigmoidf_(gc[H + jg2] + ge[H + jg2] + s1 + bh0[H + jg2]);
            float n_ = tanh_fast(gc[2 * H + jg2] + ge[2 * H + jg2] + r_ * (s2 + bh0[2 * H + jg2]));
            f4 hp = ((const f4*)sh)[A0(jg2 >> 2, fb)];
            float hprev = ((const float*)&hp)[jg2 & 3];
            h0_dst[(size_t)bg2 * H + jg2] = (1.f - z_) * n_ + z_ * hprev;
        }
    } else {
        int lb = blockIdx.x - nb0;
        int jc = lb & 31, bg = lb >> 5;
        int j0 = jc * 16, b0 = bg * 4;
        float* stX = sh;                  // x = y0(t-1)
        float* stH = sh + ST4_SZ * 4;     // h1
        stage4(h0_src + (size_t)b0 * H, stX, tid);
        stage4(h1_src + (size_t)b0 * H, stH, tid);
        __syncthreads();
        int j = tid & 15, ks = (tid >> 4) & 7, m = tid >> 7, jg = j0 + j;
        const ushort* Wm = m ? Wh1bf : Wi1bf;
        const float* stm = m ? stH : stX;
        const uint4* w0 = (const uint4*)(Wm + (size_t)jg * 512) + ks * 8;
        const uint4* w1 = (const uint4*)(Wm + (size_t)(512 + jg) * 512) + ks * 8;
        const uint4* w2 = (const uint4*)(Wm + (size_t)(1024 + jg) * 512) + ks * 8;
        float a0[4] = {}, a1[4] = {}, a2[4] = {};
#pragma unroll
        for (int c = 0; c < 8; ++c) {
            uint4 u0 = w0[c], u1 = w1[c], u2 = w2[c];
            int kq = ks * 16 + c * 2;
#pragma unroll
            for (int b = 0; b < 4; ++b) {
                f4 hA = ((const f4*)stm)[A0(kq, b)];
                f4 hB = ((const f4*)stm)[A0(kq + 1, b)];
                a0[b] += dot8bf(u0, hA, hB);
                a1[b] += dot8bf(u1, hA, hB);
                a2[b] += dot8bf(u2, hA, hB);
            }
        }
        float* part = sh + ST4_SZ * 8;  // 4352 floats in; 256*13 = 3328 floats
        {
            float* p = part + (size_t)tid * 13;
#pragma unroll
            for (int b = 0; b < 4; ++b) { p[b] = a0[b]; p[4 + b] = a1[b]; p[8 + b] = a2[b]; }
        }
        __syncthreads();
        if (tid < 64) {
            int fj = tid & 15, fb = tid >> 4;
            int jg2 = j0 + fj, bg2 = b0 + fb;
            float i0 = 0.f, i1 = 0.f, i2 = 0.f, g0 = 0.f, g1 = 0.f, g2 = 0.f;
#pragma unroll
            for (int k2 = 0; k2 < 8; ++k2) {
                const float* pi = part + (size_t)(k2 * 16 + fj) * 13;
                const float* ph = part + (size_t)((128 + k2 * 16 + fj)) * 13;
                i0 += pi[fb]; i1 += pi[4 + fb]; i2 += pi[8 + fb];
                g0 += ph[fb]; g1 += ph[4 + fb]; g2 += ph[8 + fb];
            }
            float r_ = sigmoidf_(i0 + bi1[jg2] + g0 + bh1[jg2]);
            float z_ = sigmoidf_(i1 + bi1[H + jg2] + g1 + bh1[H + jg2]);
            float n_ = tanh_fast(i2 + bi1[2 * H + jg2] + r_ * (g2 + bh1[2 * H + jg2]));
            f4 hp = ((const f4*)stH)[A0(jg2 >> 2, fb)];
            float hprev = ((const float*)&hp)[jg2 & 3];
            h1_dst[(size_t)bg2 * H + jg2] = (1.f - z_) * n_ + z_ * hprev;
        }
    }
}

__global__ void copy_hidden_kernel(const float* __restrict__ h0, const float* __restrict__ h1,
                                   float* __restrict__ dst) {
    int i = blockIdx.x * 256 + threadIdx.x;
    dst[i] = h0[i];
    dst[BH + i] = h1[i];
}

extern "C" void kernel_launch(void* const* d_in, const int* in_sizes, int n_in,
                              void* d_out_v, int out_size, void* d_ws, size_t ws_size,
                              hipStream_t stream) {
    const float* enc = (const float*)d_in[0];
    const float* hidden = (const float*)d_in[1];
    const float* target = (const float*)d_in[2];
    const float* Wq = (const float*)d_in[3];
    const float* Wk = (const float*)d_in[4];
    const float* wv = (const float*)d_in[5];
    const float* emb_W = (const float*)d_in[6];
    const float* emb_b = (const float*)d_in[7];
    const float* Wi0 = (const float*)d_in[8];
    const float* Wh0 = (const float*)d_in[9];
    const float* bi0 = (const float*)d_in[10];
    const float* bh0 = (const float*)d_in[11];
    const float* Wi1 = (const float*)d_in[12];
    const float* Wh1 = (const float*)d_in[13];
    const float* bi1 = (const float*)d_in[14];
    const float* bh1 = (const float*)d_in[15];
    const float* last_W = (const float*)d_in[16];
    const float* last_b = (const float*)d_in[17];
    const int* tmask = (const int*)d_in[18];

    float* out = (float*)d_out_v;
    float* out_hidden = out + (size_t)STEPS * B * ODIM;
    float* out_attn = out_hidden + (size_t)2 * BH;

    float* ws = (float*)d_ws;
    float* kpT = ws;                      // 2,097,152
    float* WkT = kpT + 2097152;           // 262,144
    float* gi_emb = WkT + 262144;         // 786,432
    float* gi_ctx = gi_emb + 786432;      // 49,152
    float* h0buf = gi_ctx + 49152;        // 32,768 (2x)
    float* h1buf = h0buf + 32768;         // 32,768 (2x)
    float* qbuf = h1buf + 32768;          // 16,384
    float* ctxbuf = qbuf + 16384;         // 16,384
    float* fbuf = ctxbuf + 16384;         // 8,192
    float* inpbuf = fbuf + 8192;          // 16,384
    float* spart = inpbuf + 16384;        // 32,768
    ushort* Wi0bf = (ushort*)(spart + 32768);  // 1,572,864 ushorts
    ushort* Wh0bf = Wi0bf + 1572864;           // 786,432
    ushort* Wi1bf = Wh0bf + 786432;            // 786,432
    ushort* Wh1bf = Wi1bf + 786432;            // 786,432

    // bf16 weight copies (row-major, k-fast)
    cvt_bf16_kernel<<<1536, 256, 0, stream>>>(Wi0, Wi0bf, 393216);
    cvt_bf16_kernel<<<768, 256, 0, stream>>>(Wh0, Wh0bf, 196608);
    cvt_bf16_kernel<<<768, 256, 0, stream>>>(Wi1, Wi1bf, 196608);
    cvt_bf16_kernel<<<768, 256, 0, stream>>>(Wh1, Wh1bf, 196608);

    transpose_kernel<<<dim3(16, 16), 256, 0, stream>>>(Wk, WkT, 512, 512, 512);
    kproj_gemm_kernel<<<dim3(64, 8), 256, 0, stream>>>(enc, WkT, kpT);
    init_kernel<<<B, 512, 0, stream>>>(hidden, emb_W, emb_b, h0buf, h1buf, inpbuf);

    int p0 = 0, p1 = 0;
    for (int i = 0; i < STEPS; ++i) {
        int im1 = (i > 0) ? i - 1 : 0;
        const float* h1cur = h1buf + (size_t)p1 * BH;
        attn1_kernel<<<(i > 0) ? 96 : 64, 256, 0, stream>>>(
            64, h1cur, Wq, qbuf, last_W, last_b, target + (size_t)im1 * B * ODIM,
            tmask + im1 * B, fbuf, out + (size_t)im1 * B * ODIM);
        attn2_kernel<<<(i > 0) ? 288 : 256, 256, 0, stream>>>(qbuf, kpT, wv, spart, fbuf,
                                                              emb_W, emb_b, inpbuf);
        attn3_kernel<<<256, 256, 0, stream>>>(spart, enc, ctxbuf, out_attn + (size_t)i * B * T);
        gi_kernel<<<192, 256, 0, stream>>>(ctxbuf, inpbuf, Wi0bf, bi0, gi_ctx,
                                           gi_emb + (size_t)i * B * G3);
        for (int t = 0; t <= i + 1; ++t) {
            int nb0 = (t <= i) ? 256 : 0;
            int nb1 = (t >= 1) ? 256 : 0;
            int tge = (t <= i) ? t : 0;
            cell_kernel<<<nb0 + nb1, 256, 0, stream>>>(
                nb0, h0buf + (size_t)p0 * BH, h0buf + (size_t)(p0 ^ 1) * BH,
                h1buf + (size_t)p1 * BH, h1buf + (size_t)(p1 ^ 1) * BH,
                gi_emb + (size_t)tge * B * G3, gi_ctx, Wh0bf, bh0, Wi1bf, bi1, Wh1bf, bh1);
            if (nb0) p0 ^= 1;
            if (nb1) p1 ^= 1;
        }
    }
    // final lin (step 15)
    attn1_kernel<<<32, 256, 0, stream>>>(0, h1buf + (size_t)p1 * BH, Wq, qbuf, last_W, last_b,
                                         target + (size_t)15 * B * ODIM, tmask + 15 * B, fbuf,
                                         out + (size_t)15 * B * ODIM);
    copy_hidden_kernel<<<64, 256, 0, stream>>>(h0buf + (size_t)p0 * BH, h1buf + (size_t)p1 * BH,
                                               out_hidden);
}